// Round 5
// baseline (736.908 us; speedup 1.0000x reference)
//
#include <hip/hip_runtime.h>
#include <hip/hip_bf16.h>

typedef __bf16 bf16;
typedef __attribute__((ext_vector_type(8))) __bf16 bf16x8;
typedef __attribute__((ext_vector_type(4))) __bf16 bf16x4;
typedef __attribute__((ext_vector_type(4))) float floatx4;

#define E_DIM 4096
#define H_DIM 32
#define D_DIM 128
#define M_DIM 256
#define B_DIM 8
#define N_DIM 256

// async global->LDS, 16B per lane, lds dest = wave-uniform base + lane*16
#define GLD_LDS(g, l) __builtin_amdgcn_global_load_lds( \
    (const __attribute__((address_space(1))) unsigned int*)(g), \
    (__attribute__((address_space(3))) unsigned int*)(l), 16, 0, 0)

__device__ __forceinline__ float wave_sum(float v) {
#pragma unroll
  for (int o = 32; o; o >>= 1) v += __shfl_xor(v, o);
  return v;
}
__device__ __forceinline__ float wave_max(float v) {
#pragma unroll
  for (int o = 32; o; o >>= 1) v = fmaxf(v, __shfl_xor(v, o));
  return v;
}

// ================= 256x256 8-phase GEMM core =================
// BM=BN=256, BK=64, 512 thr = 8 waves (2M x 4N). LDS 128KB. Measured R4:
// ~3.47 TF/block (941 TF effective on proj). vmcnt(4) at K-tile boundary
// leaves B(U+1)'s 4 loads in flight. Callable repeatedly (last iter vmcnt 0).
#define BAR256() asm volatile("s_barrier" ::: "memory")
#define LGKM0_256()                                      \
  asm volatile("s_waitcnt lgkmcnt(0)" ::: "memory");     \
  __builtin_amdgcn_sched_barrier(0)

#define STAGE_A256(T, h)                                                       \
  {                                                                            \
    _Pragma("unroll") for (int j = 0; j < 2; ++j)                              \
        GLD_LDS(Ag + (size_t)((h)*128 + sgrow + j * 8) * lda + (T) * 64 + sgcol, \
                AsP + ((T)&1) * 16384 + (h)*8192 + sdst + j * 512);            \
  }
#define STAGE_B256(T, h)                                                       \
  {                                                                            \
    _Pragma("unroll") for (int j = 0; j < 2; ++j)                              \
        GLD_LDS(Bg + (size_t)((h)*128 + sgrow + j * 8) * ldb + (T) * 64 + sgcol, \
                BsP + ((T)&1) * 16384 + (h)*8192 + sdst + j * 512);            \
  }
#define LDA256(mh)                                                             \
  {                                                                            \
    _Pragma("unroll") for (int m = 0; m < 4; ++m) {                            \
      a[m][0] = *(const bf16x8*)(AsP + buf + rA + ((mh)*4 + m) * 1024 + slot0); \
      a[m][1] = *(const bf16x8*)(AsP + buf + rA + ((mh)*4 + m) * 1024 + slot1); \
    }                                                                          \
  }
#define LDB256(dst, nh)                                                        \
  {                                                                            \
    _Pragma("unroll") for (int n = 0; n < 2; ++n) {                            \
      dst[n][0] = *(const bf16x8*)(BsP + buf + rB + ((nh)*2 + n) * 1024 + slot0); \
      dst[n][1] = *(const bf16x8*)(BsP + buf + rB + ((nh)*2 + n) * 1024 + slot1); \
    }                                                                          \
  }
#define MFMAQ(mb, nb, B)                                                       \
  {                                                                            \
    _Pragma("unroll") for (int m = 0; m < 4; ++m)                              \
        _Pragma("unroll") for (int n = 0; n < 2; ++n) {                        \
      acc[(mb) + m][(nb) + n] = __builtin_amdgcn_mfma_f32_16x16x32_bf16(       \
          a[m][0], B[n][0], acc[(mb) + m][(nb) + n], 0, 0, 0);                 \
      acc[(mb) + m][(nb) + n] = __builtin_amdgcn_mfma_f32_16x16x32_bf16(       \
          a[m][1], B[n][1], acc[(mb) + m][(nb) + n], 0, 0, 0);                 \
    }                                                                          \
  }

__device__ __forceinline__ void gemm256_core(const bf16* __restrict__ Ag,
                                             const bf16* __restrict__ Bg,
                                             int lda, int ldb, int nkt,
                                             bf16* AsP, bf16* BsP,
                                             floatx4 (&acc)[8][4],
                                             int wid, int lane) {
  const int wm = wid >> 2, wn = wid & 3;
  const int l15 = lane & 15, q = lane >> 4, e7 = lane & 7;
  const int slot0 = ((q ^ e7) & 7) * 8;
  const int slot1 = (((4 + q) ^ e7) & 7) * 8;
  const int rA = (wm * 128 + l15) * 64;
  const int rB = (wn * 64 + l15) * 64;
  const int sgrow = wid * 16 + (lane >> 3);
  const int sgcol = ((lane & 7) ^ (lane >> 3)) * 8;
  const int sdst = wid * 1024;  // + j*512 (elements)

  bf16x8 a[4][2], b0[2][2], b1[2][2];

  // prologue (program order matters for vmcnt counting)
  STAGE_B256(0, 0); STAGE_B256(0, 1);
  STAGE_A256(0, 0); STAGE_A256(0, 1);
  STAGE_B256(1, 0); STAGE_B256(1, 1);

  for (int U = 0; U < nkt; ++U) {
    const int buf = (U & 1) * 16384;
    if (U + 1 < nkt)
      asm volatile("s_waitcnt vmcnt(4)\n\ts_barrier" ::: "memory");
    else
      asm volatile("s_waitcnt vmcnt(0)\n\ts_barrier" ::: "memory");
    // ph0: A mh0 (8 reads) + B nh0 (4 reads); stage A(U+1)h0
    LDA256(0); LDB256(b0, 0);
    if (U + 1 < nkt) { STAGE_A256(U + 1, 0); }
    BAR256(); LGKM0_256();
    __builtin_amdgcn_s_setprio(1); MFMAQ(0, 0, b0); __builtin_amdgcn_s_setprio(0);
    __builtin_amdgcn_sched_barrier(0); BAR256();
    // ph1: B nh1 (4 reads); stage A(U+1)h1
    LDB256(b1, 1);
    if (U + 1 < nkt) { STAGE_A256(U + 1, 1); }
    BAR256(); LGKM0_256();
    __builtin_amdgcn_s_setprio(1); MFMAQ(0, 2, b1); __builtin_amdgcn_s_setprio(0);
    __builtin_amdgcn_sched_barrier(0); BAR256();
    // ph2: A mh1 (8 reads); stage B(U+2)h0
    LDA256(1);
    if (U + 2 < nkt) { STAGE_B256(U + 2, 0); }
    BAR256(); LGKM0_256();
    __builtin_amdgcn_s_setprio(1); MFMAQ(4, 2, b1); __builtin_amdgcn_s_setprio(0);
    __builtin_amdgcn_sched_barrier(0); BAR256();
    // ph3: no reads; stage B(U+2)h1
    if (U + 2 < nkt) { STAGE_B256(U + 2, 1); }
    BAR256();
    __builtin_amdgcn_s_setprio(1); MFMAQ(4, 0, b0); __builtin_amdgcn_s_setprio(0);
    __builtin_amdgcn_sched_barrier(0);
    // closing barrier of ph3 = next iteration's vmcnt+barrier
  }
}

// ---------------- k/v projection (256 blocks, ONE dispatch wave) + q split-K ----------------
__global__ __launch_bounds__(512, 1)
void proj256(const bf16* __restrict__ qin, const bf16* __restrict__ kin,
             const bf16* __restrict__ kv, const bf16* __restrict__ Wqkv,
             const float* __restrict__ bqkv, float* __restrict__ qpart,
             bf16* __restrict__ kp, bf16* __restrict__ vt) {
  __shared__ __align__(16) bf16 As2[32768];  // 64KB: 2 dbuf x 256x64
  __shared__ __align__(16) bf16 Bs2[32768];
  const int tid = threadIdx.x, wid = tid >> 6, lane = tid & 63;

  const int o = blockIdx.x;
  const int id = (o & 7) * 32 + (o >> 3);  // bijective XCD swizzle (256=8*32)
  int role, bx, by;
  const bf16 *A, *B;
  const float* bias;
  bf16* C;
  if (id < 128) {                    // k
    role = 1; by = id & 7; bx = id >> 3;
    A = kin; B = Wqkv + 16777216; bias = bqkv + 4096; C = kp;
  } else {                           // v
    role = 2; by = (id - 128) & 7; bx = (id - 128) >> 3;
    A = kv; B = Wqkv + 33554432; bias = bqkv + 8192; C = vt;
  }
  const int trowA = by * 256, trowB = bx * 256;
  const bf16* Ag = A + (size_t)trowA * E_DIM;
  const bf16* Bg = B + (size_t)trowB * E_DIM;

  floatx4 acc[8][4];
#pragma unroll
  for (int i = 0; i < 8; ++i)
#pragma unroll
    for (int j = 0; j < 4; ++j) acc[i][j] = (floatx4){0.f, 0.f, 0.f, 0.f};

  gemm256_core(Ag, Bg, E_DIM, E_DIM, 64, As2, Bs2, acc, wid, lane);

  const int wm = wid >> 2, wn = wid & 3;
  const int l15 = lane & 15, q = lane >> 4;
  const int mrow0 = trowA + wm * 128 + q * 4;
  const int ncol0 = trowB + wn * 64 + l15;
  if (role == 1) {
#pragma unroll
    for (int m = 0; m < 8; ++m)
#pragma unroll
      for (int n = 0; n < 4; ++n) {
        const int col = ncol0 + n * 16;
        const float bb = bias[col];
        floatx4 v = acc[m][n];
#pragma unroll
        for (int r = 0; r < 4; ++r)
          C[(size_t)(mrow0 + m * 16 + r) * E_DIM + col] = (bf16)(v[r] + bb);
      }
  } else {
#pragma unroll
    for (int m = 0; m < 8; ++m)
#pragma unroll
      for (int n = 0; n < 4; ++n) {
        const int col = ncol0 + n * 16;
        const int h = col >> 7, d = col & 127;
        const float bb = bias[col];
        const int row0 = mrow0 + m * 16;
        const int b_ = row0 >> 8, n_ = row0 & 255;
        floatx4 v = acc[m][n];
        bf16x4 p;
#pragma unroll
        for (int r = 0; r < 4; ++r) p[r] = (bf16)(v[r] + bb);
        *(bf16x4*)(C + ((size_t)((b_ * H_DIM + h) * D_DIM + d)) * N_DIM + n_) = p;
      }
  }

  // ---- q split-K sub-tile: col-tile qx, K-chunk kc (nkt=4) ----
  const int qx = id & 15, kc = id >> 4;
  const bf16* Agq = qin + kc * 256;                              // rows 0..255
  const bf16* Bgq = Wqkv + (size_t)(qx * 256) * E_DIM + kc * 256;
#pragma unroll
  for (int i = 0; i < 8; ++i)
#pragma unroll
    for (int j = 0; j < 4; ++j) acc[i][j] = (floatx4){0.f, 0.f, 0.f, 0.f};

  gemm256_core(Agq, Bgq, E_DIM, E_DIM, 4, As2, Bs2, acc, wid, lane);

  float* qdst = qpart + (size_t)kc * 1048576;  // [kc][256][4096] f32
  const int qmrow0 = wm * 128 + q * 4;
  const int qncol0 = qx * 256 + wn * 64 + l15;
#pragma unroll
  for (int m = 0; m < 8; ++m)
#pragma unroll
    for (int n = 0; n < 4; ++n) {
      const int col = qncol0 + n * 16;
      floatx4 v = acc[m][n];
#pragma unroll
      for (int r = 0; r < 4; ++r)
        qdst[(size_t)(qmrow0 + m * 16 + r) * E_DIM + col] = v[r];
    }
}

// ---------------- q partial reduce: qp = bf16(sum_kc qpart + bias) ----------------
__global__ __launch_bounds__(256) void qreduce_kernel(const float* __restrict__ qpart,
                                                      const float* __restrict__ bias,
                                                      bf16* __restrict__ qp) {
  const size_t i = ((size_t)blockIdx.x * 256 + threadIdx.x) * 4;  // over 1,048,576
  float4 s = *(const float4*)(bias + (i & 4095));
#pragma unroll
  for (int kc = 0; kc < 16; ++kc) {
    float4 v = *(const float4*)(qpart + (size_t)kc * 1048576 + i);
    s.x += v.x; s.y += v.y; s.z += v.z; s.w += v.w;
  }
  bf16x4 p; p[0] = (bf16)s.x; p[1] = (bf16)s.y; p[2] = (bf16)s.z; p[3] = (bf16)s.w;
  *(bf16x4*)(qp + i) = p;
}

// ---------------- scores: one (b,h) per block, 256^2 8-phase, nkt=2 ----------------
// R5: replaces 1024-small-block gemm_bt<2> (2 dispatch rounds) with 256
// blocks = one wave of the fast core.
__global__ __launch_bounds__(512, 1)
void scores256(const bf16* __restrict__ qp, const bf16* __restrict__ kp,
               float* __restrict__ scores, float scale) {
  __shared__ __align__(16) bf16 As2[32768];
  __shared__ __align__(16) bf16 Bs2[32768];
  const int tid = threadIdx.x, wid = tid >> 6, lane = tid & 63;

  const int o = blockIdx.x;
  const int z = (o & 7) * 32 + (o >> 3);  // bijective XCD swizzle
  const int zb = z >> 5, zh = z & 31;
  const bf16* Ag = qp + zh * D_DIM;
  const bf16* Bg = kp + (size_t)zb * N_DIM * E_DIM + zh * D_DIM;

  floatx4 acc[8][4];
#pragma unroll
  for (int i = 0; i < 8; ++i)
#pragma unroll
    for (int j = 0; j < 4; ++j) acc[i][j] = (floatx4){0.f, 0.f, 0.f, 0.f};

  gemm256_core(Ag, Bg, E_DIM, E_DIM, 2, As2, Bs2, acc, wid, lane);

  const int wm = wid >> 2, wn = wid & 3;
  const int l15 = lane & 15, q = lane >> 4;
  const int mrow0 = wm * 128 + q * 4;
  const int ncol0 = wn * 64 + l15;
  float* Cz = scores + (size_t)z * (M_DIM * N_DIM);
#pragma unroll
  for (int m = 0; m < 8; ++m)
#pragma unroll
    for (int n = 0; n < 4; ++n) {
      const int col = ncol0 + n * 16;
      floatx4 v = acc[m][n];
#pragma unroll
      for (int r = 0; r < 4; ++r)
        Cz[(size_t)(mrow0 + m * 16 + r) * N_DIM + col] = v[r] * scale;
    }
}

// ---------------- out-proj, 256^2 tiles, split-K=2, 256 blocks ----------------
__global__ __launch_bounds__(512, 1)
void outproj256(const bf16* __restrict__ obuf, const bf16* __restrict__ Wout,
                float* __restrict__ Cf) {
  __shared__ __align__(16) bf16 As2[32768];
  __shared__ __align__(16) bf16 Bs2[32768];
  const int tid = threadIdx.x, wid = tid >> 6, lane = tid & 63;

  const int o = blockIdx.x;
  const int id = (o & 7) * 32 + (o >> 3);  // bijective XCD swizzle (256=8*32)
  const int z = id >> 7;                   // split-K half
  const int t = id & 127;
  const int by = t & 7, bx = t >> 3;
  const int trowA = by * 256, trowB = bx * 256;
  const bf16* Ag = obuf + (size_t)z * 2048 + (size_t)trowA * E_DIM;
  const bf16* Bg = Wout + (size_t)z * 2048 + (size_t)trowB * E_DIM;

  floatx4 acc[8][4];
#pragma unroll
  for (int i = 0; i < 8; ++i)
#pragma unroll
    for (int j = 0; j < 4; ++j) acc[i][j] = (floatx4){0.f, 0.f, 0.f, 0.f};

  gemm256_core(Ag, Bg, E_DIM, E_DIM, 32, As2, Bs2, acc, wid, lane);

  const int wm = wid >> 2, wn = wid & 3;
  const int l15 = lane & 15, q = lane >> 4;
  const int mrow0 = trowA + wm * 128 + q * 4;
  const int ncol0 = trowB + wn * 64 + l15;
#pragma unroll
  for (int m = 0; m < 8; ++m)
#pragma unroll
    for (int n = 0; n < 4; ++n) {
      const int col = ncol0 + n * 16;
      floatx4 v = acc[m][n];
#pragma unroll
      for (int r = 0; r < 4; ++r)
        Cf[(size_t)z * 8388608 + (size_t)(mrow0 + m * 16 + r) * E_DIM + col] = v[r];
    }
}

// ---------------- R0 2-phase core (kept for PV batched GEMM) ----------------
__device__ __forceinline__ void gemm_core_small(const bf16* __restrict__ Arow,
                                                const bf16* __restrict__ Brow,
                                                int lda, int ldb, int kTiles,
                                                bf16* As, bf16* Bs,
                                                floatx4 (&acc)[4][4],
                                                int wid, int lane) {
  const int s0 = wid * 2;
  const int lp = lane ^ ((lane >> 3) & 7);
  const int srow = lp >> 2;
  const int skoff = (lp & 3) * 8;
  const int rA = (wid >> 1) * 64 + (lane & 15);
  const int rB = (wid & 1) * 64 + (lane & 15);
  const int q16 = (lane >> 4) * 8;
  const int ex = (((lane & 15) >> 1) & 7) << 3;

#pragma unroll
  for (int c = 0; c < 2; ++c) {
    const int s = s0 + c;
    const int row = s * 16 + srow;
    GLD_LDS(Arow + (size_t)row * lda + skoff, As + s * 512);
    GLD_LDS(Brow + (size_t)row * ldb + skoff, Bs + s * 512);
  }

  for (int kt = 0; kt < kTiles; ++kt) {
    const int cur = (kt & 1) * 4096;
    const int nxt = 4096 - cur;
    __syncthreads();
    if (kt + 1 < kTiles) {
      const int k0 = (kt + 1) << 5;
#pragma unroll
      for (int c = 0; c < 2; ++c) {
        const int s = s0 + c;
        const int row = s * 16 + srow;
        GLD_LDS(Arow + (size_t)row * lda + k0 + skoff, As + nxt + s * 512);
        GLD_LDS(Brow + (size_t)row * ldb + k0 + skoff, Bs + nxt + s * 512);
      }
    }
    bf16x8 af[4], bfr[4];
#pragma unroll
    for (int t = 0; t < 4; ++t) {
      af[t] = *(const bf16x8*)(As + cur + ((((rA + t * 16) * 32) + q16) ^ ex));
      bfr[t] = *(const bf16x8*)(Bs + cur + ((((rB + t * 16) * 32) + q16) ^ ex));
    }
#pragma unroll
    for (int tr = 0; tr < 4; ++tr)
#pragma unroll
      for (int tc = 0; tc < 4; ++tc)
        acc[tr][tc] = __builtin_amdgcn_mfma_f32_16x16x32_bf16(af[tr], bfr[tc],
                                                              acc[tr][tc], 0, 0, 0);
  }
}

// ---------------- merged prep: LN(x), LN(q), weight cvt in ONE launch ----------------
// R5: cvt_all + ln_x + ln_q were independent but serialized (~102us + gaps).
// Block ranges: [0,2048) ln_x rows; [2048,2304) ln_q rows; [2304,6400) cvt
// grid-stride x8 (4096 blocks cover 67,108,864 bf16 outputs, 2048/iter/blk).
__global__ __launch_bounds__(256) void prep_kernel(
    const float* __restrict__ x, const float* __restrict__ lnxw,
    const float* __restrict__ lnxb, const float* __restrict__ pos,
    bf16* __restrict__ kv, bf16* __restrict__ kin,
    const float* __restrict__ qsrc, const float* __restrict__ lnqw,
    const float* __restrict__ lnqb, bf16* __restrict__ qin,
    const float* __restrict__ Wqkv_f, bf16* __restrict__ Wqkv,
    const float* __restrict__ Wout_f, bf16* __restrict__ Wout) {
  const int bid = blockIdx.x;
  const int tid = threadIdx.x, wid = tid >> 6, lane = tid & 63;

  if (bid >= 2304) {  // ---- weight conversion, grid-stride ----
    const int cb = bid - 2304;
#pragma unroll
    for (int c = 0; c < 8; ++c) {
      long i = (((long)c * 4096 + cb) * 256 + tid) * 8;
      const float* src;
      bf16* dst;
      if (i < 50331648L) { src = Wqkv_f + i; dst = Wqkv + i; }
      else { src = Wout_f + (i - 50331648L); dst = Wout + (i - 50331648L); }
      float4 a = *(const float4*)(src);
      float4 b = *(const float4*)(src + 4);
      bf16x8 p;
      p[0] = (bf16)a.x; p[1] = (bf16)a.y; p[2] = (bf16)a.z; p[3] = (bf16)a.w;
      p[4] = (bf16)b.x; p[5] = (bf16)b.y; p[6] = (bf16)b.z; p[7] = (bf16)b.w;
      *(bf16x8*)(dst) = p;
    }
    return;
  }

  const bool is_q = (bid >= 2048);
  const int row = is_q ? (bid - 2048) : bid;
  const float* xr = (is_q ? qsrc : x) + (size_t)row * E_DIM;
  const float* w = is_q ? lnqw : lnxw;
  const float* bvec = is_q ? lnqb : lnxb;
  const int posrow = is_q ? row : (row & (N_DIM - 1));

  float4 v[4];
  float s1 = 0.f, s2 = 0.f;
#pragma unroll
  for (int j = 0; j < 4; ++j) {
    v[j] = *(const float4*)(xr + j * 1024 + tid * 4);
    s1 += v[j].x + v[j].y + v[j].z + v[j].w;
    s2 += v[j].x * v[j].x + v[j].y * v[j].y + v[j].z * v[j].z + v[j].w * v[j].w;
  }
  s1 = wave_sum(s1); s2 = wave_sum(s2);
  __shared__ float red[8];
  if (lane == 0) { red[wid] = s1; red[wid + 4] = s2; }
  __syncthreads();
  s1 = red[0] + red[1] + red[2] + red[3];
  s2 = red[4] + red[5] + red[6] + red[7];
  const float mean = s1 * (1.f / E_DIM);
  const float var = s2 * (1.f / E_DIM) - mean * mean;
  const float rs = rsqrtf(var + 1e-5f);
#pragma unroll
  for (int j = 0; j < 4; ++j) {
    const int idx = j * 1024 + tid * 4;
    float4 wv = *(const float4*)(w + idx);
    float4 bv = *(const float4*)(bvec + idx);
    float4 pv = *(const float4*)(pos + (size_t)posrow * E_DIM + idx);
    float y0 = (v[j].x - mean) * rs * wv.x + bv.x;
    float y1 = (v[j].y - mean) * rs * wv.y + bv.y;
    float y2 = (v[j].z - mean) * rs * wv.z + bv.z;
    float y3 = (v[j].w - mean) * rs * wv.w + bv.w;
    if (is_q) {
      bf16x4 a;
      a[0] = (bf16)(y0 + pv.x); a[1] = (bf16)(y1 + pv.y);
      a[2] = (bf16)(y2 + pv.z); a[3] = (bf16)(y3 + pv.w);
      *(bf16x4*)(qin + (size_t)row * E_DIM + idx) = a;
    } else {
      bf16x4 a; a[0] = (bf16)y0; a[1] = (bf16)y1; a[2] = (bf16)y2; a[3] = (bf16)y3;
      *(bf16x4*)(kv + (size_t)row * E_DIM + idx) = a;
      bf16x4 c; c[0] = (bf16)(y0 + pv.x); c[1] = (bf16)(y1 + pv.y);
      c[2] = (bf16)(y2 + pv.z); c[3] = (bf16)(y3 + pv.w);
      *(bf16x4*)(kin + (size_t)row * E_DIM + idx) = c;
    }
  }
}

// ---------------- BT GEMM (small K): MODE 3 PV ----------------
template <int MODE>
__global__ __launch_bounds__(256, 2)
void gemm_bt(const bf16* __restrict__ Abase, const bf16* __restrict__ Bbase,
             float* __restrict__ Cf, bf16* __restrict__ Cb,
             int K, int lda, int ldb, int ldc, float scale) {
  __shared__ __align__(16) bf16 As[8192];
  __shared__ __align__(16) bf16 Bs[8192];
  const int tid = threadIdx.x;
  const int wid = tid >> 6;
  const int lane = tid & 63;

  const bf16* A = Abase;
  const bf16* B = Bbase;
  if constexpr (MODE == 3) {
    int z = blockIdx.z;
    A += (size_t)z * M_DIM * 512;   // probs: 512-ushort row stride
    B += (size_t)z * D_DIM * N_DIM; // vt batch
  }

  const bf16* Arow = A + (size_t)(blockIdx.y * 128) * lda;
  const bf16* Brow = B + (size_t)(blockIdx.x * 128) * ldb;

  floatx4 acc[4][4];
#pragma unroll
  for (int i = 0; i < 4; ++i)
#pragma unroll
    for (int j = 0; j < 4; ++j) acc[i][j] = (floatx4){0.f, 0.f, 0.f, 0.f};

  gemm_core_small(Arow, Brow, lda, ldb, K >> 5, As, Bs, acc, wid, lane);

  const int mb = blockIdx.y * 128 + (wid >> 1) * 64 + (lane >> 4) * 4;
  const int nb = blockIdx.x * 128 + (wid & 1) * 64 + (lane & 15);
#pragma unroll
  for (int tr = 0; tr < 4; ++tr) {
#pragma unroll
    for (int tc = 0; tc < 4; ++tc) {
      const int row0 = mb + tr * 16;
      const int col = nb + tc * 16;
      floatx4 a = acc[tr][tc];
      int z = blockIdx.z; int zb_ = z >> 5, zh_ = z & 31;
#pragma unroll
      for (int r = 0; r < 4; ++r)
        Cb[(size_t)zb_ * M_DIM * E_DIM + (size_t)(row0 + r) * E_DIM + zh_ * D_DIM + col] =
            (bf16)a[r];
    }
  }
}

// ---------------- split-K reduce: out = p0 + p1 + bias ----------------
__global__ __launch_bounds__(256) void reduce_out_kernel(const float* __restrict__ p,
                                                         const float* __restrict__ bias,
                                                         float* __restrict__ out) {
  const size_t i = ((size_t)blockIdx.x * 256 + threadIdx.x) * 4;
  float4 a = *(const float4*)(p + i);
  float4 b = *(const float4*)(p + 8388608 + i);
  float4 bb = *(const float4*)(bias + (i & 4095));
  float4 o;
  o.x = a.x + b.x + bb.x; o.y = a.y + b.y + bb.y;
  o.z = a.z + b.z + bb.z; o.w = a.w + b.w + bb.w;
  *(float4*)(out + i) = o;
}

// ---------------- softmax over N per (b,m) for all heads + head-mean ----------------
__global__ __launch_bounds__(256) void softmax_mean_kernel(float* __restrict__ scores,
                                                           float* __restrict__ out_mean) {
  const int bm = blockIdx.x;  // b*256 + m
  const int b = bm >> 8, m = bm & 255;
  const int wid = threadIdx.x >> 6, lane = threadIdx.x & 63;
  float a0 = 0.f, a1 = 0.f, a2 = 0.f, a3 = 0.f;
  for (int j = 0; j < 8; ++j) {
    const int h = wid * 8 + j;
    float* row = scores + ((size_t)((b * H_DIM + h) * M_DIM + m)) * N_DIM;
    float4 v = *(const float4*)(row + lane * 4);
    float mx = fmaxf(fmaxf(v.x, v.y), fmaxf(v.z, v.w));
    mx = wave_max(mx);
    v.x = __expf(v.x - mx); v.y = __expf(v.y - mx);
    v.z = __expf(v.z - mx); v.w = __expf(v.w - mx);
    const float s = wave_sum(v.x + v.y + v.z + v.w);
    const float inv = 1.f / s;
    v.x *= inv; v.y *= inv; v.z *= inv; v.w *= inv;
    a0 += v.x; a1 += v.y; a2 += v.z; a3 += v.w;
    bf16x4 p; p[0] = (bf16)v.x; p[1] = (bf16)v.y; p[2] = (bf16)v.z; p[3] = (bf16)v.w;
    *(bf16x4*)((bf16*)row + lane * 4) = p;  // in-place: first 512B of the 1KB row
  }
  __shared__ float red[4][256];
  *(float4*)&red[wid][lane * 4] = make_float4(a0, a1, a2, a3);
  __syncthreads();
  if (wid == 0) {
    float4 r0 = *(float4*)&red[0][lane * 4];
    float4 r1 = *(float4*)&red[1][lane * 4];
    float4 r2 = *(float4*)&red[2][lane * 4];
    float4 r3 = *(float4*)&red[3][lane * 4];
    float4 o;
    o.x = (r0.x + r1.x + r2.x + r3.x) * (1.f / H_DIM);
    o.y = (r0.y + r1.y + r2.y + r3.y) * (1.f / H_DIM);
    o.z = (r0.z + r1.z + r2.z + r3.z) * (1.f / H_DIM);
    o.w = (r0.w + r1.w + r2.w + r3.w) * (1.f / H_DIM);
    *(float4*)(out_mean + (size_t)bm * N_DIM + lane * 4) = o;
  }
}

extern "C" void kernel_launch(void* const* d_in, const int* in_sizes, int n_in,
                              void* d_out, int out_size, void* d_ws, size_t ws_size,
                              hipStream_t stream) {
  const float* x = (const float*)d_in[0];
  const float* query = (const float*)d_in[1];
  const float* pos = (const float*)d_in[2];
  const float* ln_q_w = (const float*)d_in[3];
  const float* ln_q_b = (const float*)d_in[4];
  const float* ln_kv_w = (const float*)d_in[5];
  const float* ln_kv_b = (const float*)d_in[6];
  const float* Wqkv_f = (const float*)d_in[7];
  const float* bqkv = (const float*)d_in[8];
  const float* Wout_f = (const float*)d_in[9];
  const float* bout = (const float*)d_in[10];

  char* ws = (char*)d_ws;
  bf16* Wqkv = (bf16*)(ws + 0);            // 100,663,296
  bf16* Wout = (bf16*)(ws + 100663296);    // 33,554,432
  bf16* kv   = (bf16*)(ws + 134217728);    // 16,777,216
  bf16* kin  = (bf16*)(ws + 150994944);    // 16,777,216
  bf16* qin  = (bf16*)(ws + 167772160);    //  2,097,152
  bf16* qp   = (bf16*)(ws + 169869312);    //  2,097,152
  bf16* kp   = (bf16*)(ws + 171966464);    // 16,777,216
  bf16* vt   = (bf16*)(ws + 188743680);    // 16,777,216
  float* partials = (float*)(ws + 205520896); // 67,108,864 -> end 272,629,760
  float* qpart = partials;                 // q split-K partials (64 MB),
                                           // free until outproj overwrites
  float* scores = (float*)(ws + 0);        // 67,108,864 (alias Wqkv)
  bf16* obuf = (bf16*)(ws + 67108864);     // 16,777,216 (alias Wqkv tail)

  float* out = (float*)d_out;
  float* out2 = out + (size_t)B_DIM * M_DIM * E_DIM;

  // LN(x), LN(q), weight conversion: one merged launch
  prep_kernel<<<6400, 256, 0, stream>>>(x, ln_kv_w, ln_kv_b, pos, kv, kin,
                                        query, ln_q_w, ln_q_b, qin,
                                        Wqkv_f, Wqkv, Wout_f, Wout);

  // k/v projections (256 blocks = one dispatch wave) + q split-K partials
  proj256<<<256, 512, 0, stream>>>(qin, kin, kv, Wqkv, bqkv, qpart, kp, vt);
  qreduce_kernel<<<1024, 256, 0, stream>>>(qpart, bqkv, qp);

  // scores[b,h,m,n] = q.k/sqrt(128): one (b,h) per block, one wave
  scores256<<<256, 512, 0, stream>>>(qp, kp, scores, 0.08838834764831845f);
  softmax_mean_kernel<<<2048, 256, 0, stream>>>(scores, out2);
  // o = probs @ v   (per (b,h): 256x128x256)
  gemm_bt<3><<<dim3(1, 2, 256), 256, 0, stream>>>((const bf16*)scores, vt,
                                                  nullptr, obuf,
                                                  256, 512, 256, 4096, 1.f);
  // out partials = o @ Wout^T, split-K=2, 256^2 8-phase (256 blocks = one wave)
  outproj256<<<256, 512, 0, stream>>>(obuf, Wout, partials);
  reduce_out_kernel<<<8192, 256, 0, stream>>>(partials, bout, out);
}

// Round 6
// 722.540 us; speedup vs baseline: 1.0199x; 1.0199x over previous
//
#include <hip/hip_runtime.h>
#include <hip/hip_bf16.h>

typedef __bf16 bf16;
typedef __attribute__((ext_vector_type(8))) __bf16 bf16x8;
typedef __attribute__((ext_vector_type(4))) __bf16 bf16x4;
typedef __attribute__((ext_vector_type(4))) float floatx4;

#define E_DIM 4096
#define H_DIM 32
#define D_DIM 128
#define M_DIM 256
#define B_DIM 8
#define N_DIM 256

// async global->LDS, 16B per lane, lds dest = wave-uniform base + lane*16
#define GLD_LDS(g, l) __builtin_amdgcn_global_load_lds( \
    (const __attribute__((address_space(1))) unsigned int*)(g), \
    (__attribute__((address_space(3))) unsigned int*)(l), 16, 0, 0)

__device__ __forceinline__ float wave_sum(float v) {
#pragma unroll
  for (int o = 32; o; o >>= 1) v += __shfl_xor(v, o);
  return v;
}

// ================= 256x256 8-phase GEMM core (proven R4: ~3.47 TF/block) ======
#define BAR256() asm volatile("s_barrier" ::: "memory")
#define LGKM0_256()                                      \
  asm volatile("s_waitcnt lgkmcnt(0)" ::: "memory");     \
  __builtin_amdgcn_sched_barrier(0)

#define STAGE_A256(T, h)                                                       \
  {                                                                            \
    _Pragma("unroll") for (int j = 0; j < 2; ++j)                              \
        GLD_LDS(Ag + (size_t)((h)*128 + sgrow + j * 8) * lda + (T) * 64 + sgcol, \
                AsP + ((T)&1) * 16384 + (h)*8192 + sdst + j * 512);            \
  }
#define STAGE_B256(T, h)                                                       \
  {                                                                            \
    _Pragma("unroll") for (int j = 0; j < 2; ++j)                              \
        GLD_LDS(Bg + (size_t)((h)*128 + sgrow + j * 8) * ldb + (T) * 64 + sgcol, \
                BsP + ((T)&1) * 16384 + (h)*8192 + sdst + j * 512);            \
  }
#define LDA256(mh)                                                             \
  {                                                                            \
    _Pragma("unroll") for (int m = 0; m < 4; ++m) {                            \
      a[m][0] = *(const bf16x8*)(AsP + buf + rA + ((mh)*4 + m) * 1024 + slot0); \
      a[m][1] = *(const bf16x8*)(AsP + buf + rA + ((mh)*4 + m) * 1024 + slot1); \
    }                                                                          \
  }
#define LDB256(dst, nh)                                                        \
  {                                                                            \
    _Pragma("unroll") for (int n = 0; n < 2; ++n) {                            \
      dst[n][0] = *(const bf16x8*)(BsP + buf + rB + ((nh)*2 + n) * 1024 + slot0); \
      dst[n][1] = *(const bf16x8*)(BsP + buf + rB + ((nh)*2 + n) * 1024 + slot1); \
    }                                                                          \
  }
#define MFMAQ(mb, nb, B)                                                       \
  {                                                                            \
    _Pragma("unroll") for (int m = 0; m < 4; ++m)                              \
        _Pragma("unroll") for (int n = 0; n < 2; ++n) {                        \
      acc[(mb) + m][(nb) + n] = __builtin_amdgcn_mfma_f32_16x16x32_bf16(       \
          a[m][0], B[n][0], acc[(mb) + m][(nb) + n], 0, 0, 0);                 \
      acc[(mb) + m][(nb) + n] = __builtin_amdgcn_mfma_f32_16x16x32_bf16(       \
          a[m][1], B[n][1], acc[(mb) + m][(nb) + n], 0, 0, 0);                 \
    }                                                                          \
  }

__device__ __forceinline__ void gemm256_core(const bf16* __restrict__ Ag,
                                             const bf16* __restrict__ Bg,
                                             int lda, int ldb, int nkt,
                                             bf16* AsP, bf16* BsP,
                                             floatx4 (&acc)[8][4],
                                             int wid, int lane) {
  const int wm = wid >> 2, wn = wid & 3;
  const int l15 = lane & 15, q = lane >> 4, e7 = lane & 7;
  const int slot0 = ((q ^ e7) & 7) * 8;
  const int slot1 = (((4 + q) ^ e7) & 7) * 8;
  const int rA = (wm * 128 + l15) * 64;
  const int rB = (wn * 64 + l15) * 64;
  const int sgrow = wid * 16 + (lane >> 3);
  const int sgcol = ((lane & 7) ^ (lane >> 3)) * 8;
  const int sdst = wid * 1024;

  bf16x8 a[4][2], b0[2][2], b1[2][2];

  STAGE_B256(0, 0); STAGE_B256(0, 1);
  STAGE_A256(0, 0); STAGE_A256(0, 1);
  STAGE_B256(1, 0); STAGE_B256(1, 1);

  for (int U = 0; U < nkt; ++U) {
    const int buf = (U & 1) * 16384;
    if (U + 1 < nkt)
      asm volatile("s_waitcnt vmcnt(4)\n\ts_barrier" ::: "memory");
    else
      asm volatile("s_waitcnt vmcnt(0)\n\ts_barrier" ::: "memory");
    LDA256(0); LDB256(b0, 0);
    if (U + 1 < nkt) { STAGE_A256(U + 1, 0); }
    BAR256(); LGKM0_256();
    __builtin_amdgcn_s_setprio(1); MFMAQ(0, 0, b0); __builtin_amdgcn_s_setprio(0);
    __builtin_amdgcn_sched_barrier(0); BAR256();
    LDB256(b1, 1);
    if (U + 1 < nkt) { STAGE_A256(U + 1, 1); }
    BAR256(); LGKM0_256();
    __builtin_amdgcn_s_setprio(1); MFMAQ(0, 2, b1); __builtin_amdgcn_s_setprio(0);
    __builtin_amdgcn_sched_barrier(0); BAR256();
    LDA256(1);
    if (U + 2 < nkt) { STAGE_B256(U + 2, 0); }
    BAR256(); LGKM0_256();
    __builtin_amdgcn_s_setprio(1); MFMAQ(4, 2, b1); __builtin_amdgcn_s_setprio(0);
    __builtin_amdgcn_sched_barrier(0); BAR256();
    if (U + 2 < nkt) { STAGE_B256(U + 2, 1); }
    BAR256();
    __builtin_amdgcn_s_setprio(1); MFMAQ(4, 0, b0); __builtin_amdgcn_s_setprio(0);
    __builtin_amdgcn_sched_barrier(0);
  }
}

// ================= 128x256 3-phase core (R6, out-proj no-split-K) =============
// BM=128, BN=256, BK=64. Same LDS swizzle/staging geometry; B path identical
// to 256-core. Per K-tile: ph0 {LDA8+LDBnh0, stage A(U+1), 16 MFMA},
// ph1 {LDBnh1, 8 MFMA}, ph2 {stage B(U+2) both halves, 8 MFMA}.
// vmcnt invariant: boundary outstanding = B(U)4+A(U)2+B(U+1)4 = 10;
// vmcnt(4) drains exactly A(U),B(U), leaves B(U+1). B(U+2) staged only
// after ph1's closing barrier (all B(U) reads done) -- same anti-race rule.
#define STAGE_A128(T)                                                          \
  {                                                                            \
    _Pragma("unroll") for (int j = 0; j < 2; ++j)                              \
        GLD_LDS(Ag + (size_t)(sgrow + j * 8) * lda + (T) * 64 + sgcol,         \
                AsP + ((T)&1) * 8192 + sdst + j * 512);                        \
  }
#define LDA128()                                                               \
  {                                                                            \
    _Pragma("unroll") for (int m = 0; m < 4; ++m) {                            \
      a[m][0] = *(const bf16x8*)(AsP + bufA + rA + m * 1024 + slot0);          \
      a[m][1] = *(const bf16x8*)(AsP + bufA + rA + m * 1024 + slot1);          \
    }                                                                          \
  }
#define MFMAH(nb, bh)                                                          \
  {                                                                            \
    _Pragma("unroll") for (int m = 0; m < 4; ++m) {                            \
      acc[m][nb] = __builtin_amdgcn_mfma_f32_16x16x32_bf16(a[m][0], bh[0],     \
                                                           acc[m][nb], 0, 0, 0); \
      acc[m][nb] = __builtin_amdgcn_mfma_f32_16x16x32_bf16(a[m][1], bh[1],     \
                                                           acc[m][nb], 0, 0, 0); \
    }                                                                          \
  }

__device__ __forceinline__ void gemm128_core(const bf16* __restrict__ Ag,
                                             const bf16* __restrict__ Bg,
                                             int lda, int ldb, int nkt,
                                             bf16* AsP, bf16* BsP,
                                             floatx4 (&acc)[4][4],
                                             int wid, int lane) {
  const int wm = wid >> 2, wn = wid & 3;
  const int l15 = lane & 15, q = lane >> 4, e7 = lane & 7;
  const int slot0 = ((q ^ e7) & 7) * 8;
  const int slot1 = (((4 + q) ^ e7) & 7) * 8;
  const int rA = (wm * 64 + l15) * 64;
  const int rB = (wn * 64 + l15) * 64;
  const int sgrow = wid * 16 + (lane >> 3);
  const int sgcol = ((lane & 7) ^ (lane >> 3)) * 8;
  const int sdst = wid * 1024;

  bf16x8 a[4][2], b0[2][2], b1[2][2];

  // prologue: 10 loads -> first boundary vmcnt(4) is steady-state
  STAGE_B256(0, 0); STAGE_B256(0, 1);
  STAGE_A128(0);
  STAGE_B256(1, 0); STAGE_B256(1, 1);

  for (int U = 0; U < nkt; ++U) {
    const int buf = (U & 1) * 16384;
    const int bufA = (U & 1) * 8192;
    if (U + 1 < nkt)
      asm volatile("s_waitcnt vmcnt(4)\n\ts_barrier" ::: "memory");
    else
      asm volatile("s_waitcnt vmcnt(0)\n\ts_barrier" ::: "memory");
    // ph0: A frags (8 reads) + B nh0 (4); stage A(U+1); 16 MFMA
    LDA128(); LDB256(b0, 0);
    if (U + 1 < nkt) { STAGE_A128(U + 1); }
    BAR256(); LGKM0_256();
    __builtin_amdgcn_s_setprio(1); MFMAQ(0, 0, b0); __builtin_amdgcn_s_setprio(0);
    __builtin_amdgcn_sched_barrier(0); BAR256();
    // ph1: B nh1 (4 reads); 8 MFMA (n=2)
    LDB256(b1, 1);
    BAR256(); LGKM0_256();
    __builtin_amdgcn_s_setprio(1); MFMAH(2, b1[0]); __builtin_amdgcn_s_setprio(0);
    __builtin_amdgcn_sched_barrier(0); BAR256();
    // ph2: stage B(U+2) both halves (after all B(U) reads); 8 MFMA (n=3)
    if (U + 2 < nkt) { STAGE_B256(U + 2, 0); STAGE_B256(U + 2, 1); }
    BAR256();
    __builtin_amdgcn_s_setprio(1); MFMAH(3, b1[1]); __builtin_amdgcn_s_setprio(0);
    __builtin_amdgcn_sched_barrier(0);
  }
}

// ---------------- k/v projection (256 blocks, one wave) + q split-K ----------------
__global__ __launch_bounds__(512, 1)
void proj256(const bf16* __restrict__ qin, const bf16* __restrict__ kin,
             const bf16* __restrict__ kv, const bf16* __restrict__ Wqkv,
             const float* __restrict__ bqkv, float* __restrict__ qpart,
             bf16* __restrict__ kp, bf16* __restrict__ vt) {
  __shared__ __align__(16) bf16 As2[32768];
  __shared__ __align__(16) bf16 Bs2[32768];
  const int tid = threadIdx.x, wid = tid >> 6, lane = tid & 63;

  const int o = blockIdx.x;
  const int id = (o & 7) * 32 + (o >> 3);
  int role, bx, by;
  const bf16 *A, *B;
  const float* bias;
  bf16* C;
  if (id < 128) {                    // k
    role = 1; by = id & 7; bx = id >> 3;
    A = kin; B = Wqkv + 16777216; bias = bqkv + 4096; C = kp;
  } else {                           // v
    role = 2; by = (id - 128) & 7; bx = (id - 128) >> 3;
    A = kv; B = Wqkv + 33554432; bias = bqkv + 8192; C = vt;
  }
  const int trowA = by * 256, trowB = bx * 256;
  const bf16* Ag = A + (size_t)trowA * E_DIM;
  const bf16* Bg = B + (size_t)trowB * E_DIM;

  floatx4 acc[8][4];
#pragma unroll
  for (int i = 0; i < 8; ++i)
#pragma unroll
    for (int j = 0; j < 4; ++j) acc[i][j] = (floatx4){0.f, 0.f, 0.f, 0.f};

  gemm256_core(Ag, Bg, E_DIM, E_DIM, 64, As2, Bs2, acc, wid, lane);

  const int wm = wid >> 2, wn = wid & 3;
  const int l15 = lane & 15, q = lane >> 4;
  const int mrow0 = trowA + wm * 128 + q * 4;
  const int ncol0 = trowB + wn * 64 + l15;
  if (role == 1) {
#pragma unroll
    for (int m = 0; m < 8; ++m)
#pragma unroll
      for (int n = 0; n < 4; ++n) {
        const int col = ncol0 + n * 16;
        const float bb = bias[col];
        floatx4 v = acc[m][n];
#pragma unroll
        for (int r = 0; r < 4; ++r)
          C[(size_t)(mrow0 + m * 16 + r) * E_DIM + col] = (bf16)(v[r] + bb);
      }
  } else {
#pragma unroll
    for (int m = 0; m < 8; ++m)
#pragma unroll
      for (int n = 0; n < 4; ++n) {
        const int col = ncol0 + n * 16;
        const int h = col >> 7, d = col & 127;
        const float bb = bias[col];
        const int row0 = mrow0 + m * 16;
        const int b_ = row0 >> 8, n_ = row0 & 255;
        floatx4 v = acc[m][n];
        bf16x4 p;
#pragma unroll
        for (int r = 0; r < 4; ++r) p[r] = (bf16)(v[r] + bb);
        *(bf16x4*)(C + ((size_t)((b_ * H_DIM + h) * D_DIM + d)) * N_DIM + n_) = p;
      }
  }

  // q split-K sub-tile: col-tile qx, K-chunk kc (nkt=4)
  const int qx = id & 15, kc = id >> 4;
  const bf16* Agq = qin + kc * 256;
  const bf16* Bgq = Wqkv + (size_t)(qx * 256) * E_DIM + kc * 256;
#pragma unroll
  for (int i = 0; i < 8; ++i)
#pragma unroll
    for (int j = 0; j < 4; ++j) acc[i][j] = (floatx4){0.f, 0.f, 0.f, 0.f};

  gemm256_core(Agq, Bgq, E_DIM, E_DIM, 4, As2, Bs2, acc, wid, lane);

  float* qdst = qpart + (size_t)kc * 1048576;
  const int qmrow0 = wm * 128 + q * 4;
  const int qncol0 = qx * 256 + wn * 64 + l15;
#pragma unroll
  for (int m = 0; m < 8; ++m)
#pragma unroll
    for (int n = 0; n < 4; ++n) {
      const int col = qncol0 + n * 16;
      floatx4 v = acc[m][n];
#pragma unroll
      for (int r = 0; r < 4; ++r)
        qdst[(size_t)(qmrow0 + m * 16 + r) * E_DIM + col] = v[r];
    }
}

// ---------------- q partial reduce ----------------
__global__ __launch_bounds__(256) void qreduce_kernel(const float* __restrict__ qpart,
                                                      const float* __restrict__ bias,
                                                      bf16* __restrict__ qp) {
  const size_t i = ((size_t)blockIdx.x * 256 + threadIdx.x) * 4;
  float4 s = *(const float4*)(bias + (i & 4095));
#pragma unroll
  for (int kc = 0; kc < 16; ++kc) {
    float4 v = *(const float4*)(qpart + (size_t)kc * 1048576 + i);
    s.x += v.x; s.y += v.y; s.z += v.z; s.w += v.w;
  }
  bf16x4 p; p[0] = (bf16)s.x; p[1] = (bf16)s.y; p[2] = (bf16)s.z; p[3] = (bf16)s.w;
  *(bf16x4*)(qp + i) = p;
}

// ---------------- scores + softmax fused: probs bf16 out ----------------
// R6: each block holds the full (b,h) 256x256 score tile in registers;
// row-softmax via shfl_xor(1,2,4,8) within 16-lane col-groups + 256x4 LDS
// cross-wave combine (reuses As2). Kills the 64MB f32 re-read of the old
// softmax kernel. probs[z][m][n] bf16, row stride 256.
__global__ __launch_bounds__(512, 1)
void scores_sm(const bf16* __restrict__ qp, const bf16* __restrict__ kp,
               bf16* __restrict__ probs, float scale) {
  __shared__ __align__(16) bf16 As2[32768];
  __shared__ __align__(16) bf16 Bs2[32768];
  const int tid = threadIdx.x, wid = tid >> 6, lane = tid & 63;

  const int o = blockIdx.x;
  const int z = (o & 7) * 32 + (o >> 3);
  const int zb = z >> 5, zh = z & 31;
  const bf16* Ag = qp + zh * D_DIM;
  const bf16* Bg = kp + (size_t)zb * N_DIM * E_DIM + zh * D_DIM;

  floatx4 acc[8][4];
#pragma unroll
  for (int i = 0; i < 8; ++i)
#pragma unroll
    for (int j = 0; j < 4; ++j) acc[i][j] = (floatx4){0.f, 0.f, 0.f, 0.f};

  gemm256_core(Ag, Bg, E_DIM, E_DIM, 2, As2, Bs2, acc, wid, lane);

  const int wm = wid >> 2, wn = wid & 3;
  const int l15 = lane & 15, q = lane >> 4;

#pragma unroll
  for (int m = 0; m < 8; ++m)
#pragma unroll
    for (int n = 0; n < 4; ++n) acc[m][n] *= scale;

  // per-lane row max over the 4 n-cols, then reduce over the 16-lane group
  float vmax[8][4];
#pragma unroll
  for (int m = 0; m < 8; ++m)
#pragma unroll
    for (int r = 0; r < 4; ++r)
      vmax[m][r] = fmaxf(fmaxf(acc[m][0][r], acc[m][1][r]),
                         fmaxf(acc[m][2][r], acc[m][3][r]));
#pragma unroll
  for (int mask = 1; mask < 16; mask <<= 1)
#pragma unroll
    for (int m = 0; m < 8; ++m)
#pragma unroll
      for (int r = 0; r < 4; ++r)
        vmax[m][r] = fmaxf(vmax[m][r], __shfl_xor(vmax[m][r], mask));

  float* red = (float*)As2;  // [256][4] max, [256][4] sum at +1024
  __syncthreads();
  if (l15 == 0) {
#pragma unroll
    for (int m = 0; m < 8; ++m)
#pragma unroll
      for (int r = 0; r < 4; ++r)
        red[(wm * 128 + m * 16 + q * 4 + r) * 4 + wn] = vmax[m][r];
  }
  __syncthreads();
  float rmax[8][4];
#pragma unroll
  for (int m = 0; m < 8; ++m)
#pragma unroll
    for (int r = 0; r < 4; ++r) {
      const int row = wm * 128 + m * 16 + q * 4 + r;
      rmax[m][r] = fmaxf(fmaxf(red[row * 4 + 0], red[row * 4 + 1]),
                         fmaxf(red[row * 4 + 2], red[row * 4 + 3]));
    }

  // exp + row sum (same reduction path); acc becomes exp values
  float vsum[8][4];
#pragma unroll
  for (int m = 0; m < 8; ++m)
#pragma unroll
    for (int r = 0; r < 4; ++r) {
      float s = 0.f;
#pragma unroll
      for (int n = 0; n < 4; ++n) {
        float e = __expf(acc[m][n][r] - rmax[m][r]);
        acc[m][n][r] = e;
        s += e;
      }
      vsum[m][r] = s;
    }
#pragma unroll
  for (int mask = 1; mask < 16; mask <<= 1)
#pragma unroll
    for (int m = 0; m < 8; ++m)
#pragma unroll
      for (int r = 0; r < 4; ++r)
        vsum[m][r] += __shfl_xor(vsum[m][r], mask);
  if (l15 == 0) {
#pragma unroll
    for (int m = 0; m < 8; ++m)
#pragma unroll
      for (int r = 0; r < 4; ++r)
        red[1024 + (wm * 128 + m * 16 + q * 4 + r) * 4 + wn] = vsum[m][r];
  }
  __syncthreads();

  bf16* P = probs + (size_t)z * (M_DIM * N_DIM);
#pragma unroll
  for (int m = 0; m < 8; ++m)
#pragma unroll
    for (int r = 0; r < 4; ++r) {
      const int row = wm * 128 + m * 16 + q * 4 + r;
      const float tot = red[1024 + row * 4 + 0] + red[1024 + row * 4 + 1] +
                        red[1024 + row * 4 + 2] + red[1024 + row * 4 + 3];
      const float inv = 1.f / tot;
#pragma unroll
      for (int n = 0; n < 4; ++n)
        P[(size_t)row * N_DIM + wn * 64 + l15 + n * 16] =
            (bf16)(acc[m][n][r] * inv);
    }
}

// ---------------- head-mean of probs -> out2 ----------------
__global__ __launch_bounds__(256) void probs_mean(const bf16* __restrict__ probs,
                                                  float* __restrict__ out2) {
  const int bm = blockIdx.x;  // b*256+m
  const int b = bm >> 8, m = bm & 255;
  const int n = threadIdx.x;
  float s = 0.f;
#pragma unroll
  for (int h = 0; h < H_DIM; ++h)
    s += (float)probs[((size_t)(b * H_DIM + h) * M_DIM + m) * N_DIM + n];
  out2[(size_t)bm * N_DIM + n] = s * (1.f / H_DIM);
}

// ---------------- out-proj: 128x256 tiles, no split-K, 256 blocks ----------------
__global__ __launch_bounds__(512, 1)
void outproj128(const bf16* __restrict__ obuf, const bf16* __restrict__ Wout,
                const float* __restrict__ bout, float* __restrict__ out) {
  __shared__ __align__(16) bf16 As2[16384];  // 32KB: 2 dbuf x 128x64
  __shared__ __align__(16) bf16 Bs2[32768];  // 64KB: 2 dbuf x 256x64
  const int tid = threadIdx.x, wid = tid >> 6, lane = tid & 63;

  const int o = blockIdx.x;
  const int id = (o & 7) * 32 + (o >> 3);  // bijective XCD swizzle
  const int mt = id >> 4, nt = id & 15;    // 16 x 16 tiles
  const bf16* Ag = obuf + (size_t)(mt * 128) * E_DIM;
  const bf16* Bg = Wout + (size_t)(nt * 256) * E_DIM;

  floatx4 acc[4][4];
#pragma unroll
  for (int i = 0; i < 4; ++i)
#pragma unroll
    for (int j = 0; j < 4; ++j) acc[i][j] = (floatx4){0.f, 0.f, 0.f, 0.f};

  gemm128_core(Ag, Bg, E_DIM, E_DIM, 64, As2, Bs2, acc, wid, lane);

  const int wm = wid >> 2, wn = wid & 3;
  const int l15 = lane & 15, q4 = lane >> 4;
  const int mrow0 = mt * 128 + wm * 64 + q4 * 4;
  const int ncol0 = nt * 256 + wn * 64 + l15;
#pragma unroll
  for (int m = 0; m < 4; ++m)
#pragma unroll
    for (int n = 0; n < 4; ++n) {
      const int col = ncol0 + n * 16;
      const float bb = bout[col];
      floatx4 v = acc[m][n];
#pragma unroll
      for (int r = 0; r < 4; ++r)
        out[(size_t)(mrow0 + m * 16 + r) * E_DIM + col] = v[r] + bb;
    }
}

// ---------------- R0 2-phase core (kept for PV batched GEMM) ----------------
__device__ __forceinline__ void gemm_core_small(const bf16* __restrict__ Arow,
                                                const bf16* __restrict__ Brow,
                                                int lda, int ldb, int kTiles,
                                                bf16* As, bf16* Bs,
                                                floatx4 (&acc)[4][4],
                                                int wid, int lane) {
  const int s0 = wid * 2;
  const int lp = lane ^ ((lane >> 3) & 7);
  const int srow = lp >> 2;
  const int skoff = (lp & 3) * 8;
  const int rA = (wid >> 1) * 64 + (lane & 15);
  const int rB = (wid & 1) * 64 + (lane & 15);
  const int q16 = (lane >> 4) * 8;
  const int ex = (((lane & 15) >> 1) & 7) << 3;

#pragma unroll
  for (int c = 0; c < 2; ++c) {
    const int s = s0 + c;
    const int row = s * 16 + srow;
    GLD_LDS(Arow + (size_t)row * lda + skoff, As + s * 512);
    GLD_LDS(Brow + (size_t)row * ldb + skoff, Bs + s * 512);
  }

  for (int kt = 0; kt < kTiles; ++kt) {
    const int cur = (kt & 1) * 4096;
    const int nxt = 4096 - cur;
    __syncthreads();
    if (kt + 1 < kTiles) {
      const int k0 = (kt + 1) << 5;
#pragma unroll
      for (int c = 0; c < 2; ++c) {
        const int s = s0 + c;
        const int row = s * 16 + srow;
        GLD_LDS(Arow + (size_t)row * lda + k0 + skoff, As + nxt + s * 512);
        GLD_LDS(Brow + (size_t)row * ldb + k0 + skoff, Bs + nxt + s * 512);
      }
    }
    bf16x8 af[4], bfr[4];
#pragma unroll
    for (int t = 0; t < 4; ++t) {
      af[t] = *(const bf16x8*)(As + cur + ((((rA + t * 16) * 32) + q16) ^ ex));
      bfr[t] = *(const bf16x8*)(Bs + cur + ((((rB + t * 16) * 32) + q16) ^ ex));
    }
#pragma unroll
    for (int tr = 0; tr < 4; ++tr)
#pragma unroll
      for (int tc = 0; tc < 4; ++tc)
        acc[tr][tc] = __builtin_amdgcn_mfma_f32_16x16x32_bf16(af[tr], bfr[tc],
                                                              acc[tr][tc], 0, 0, 0);
  }
}

// ---------------- merged prep: LN(x), LN(q), weight cvt ----------------
__global__ __launch_bounds__(256) void prep_kernel(
    const float* __restrict__ x, const float* __restrict__ lnxw,
    const float* __restrict__ lnxb, const float* __restrict__ pos,
    bf16* __restrict__ kv, bf16* __restrict__ kin,
    const float* __restrict__ qsrc, const float* __restrict__ lnqw,
    const float* __restrict__ lnqb, bf16* __restrict__ qin,
    const float* __restrict__ Wqkv_f, bf16* __restrict__ Wqkv,
    const float* __restrict__ Wout_f, bf16* __restrict__ Wout) {
  const int bid = blockIdx.x;
  const int tid = threadIdx.x, wid = tid >> 6, lane = tid & 63;

  if (bid >= 2304) {  // weight conversion, grid-stride
    const int cb = bid - 2304;
#pragma unroll
    for (int c = 0; c < 8; ++c) {
      long i = (((long)c * 4096 + cb) * 256 + tid) * 8;
      const float* src;
      bf16* dst;
      if (i < 50331648L) { src = Wqkv_f + i; dst = Wqkv + i; }
      else { src = Wout_f + (i - 50331648L); dst = Wout + (i - 50331648L); }
      float4 a = *(const float4*)(src);
      float4 b = *(const float4*)(src + 4);
      bf16x8 p;
      p[0] = (bf16)a.x; p[1] = (bf16)a.y; p[2] = (bf16)a.z; p[3] = (bf16)a.w;
      p[4] = (bf16)b.x; p[5] = (bf16)b.y; p[6] = (bf16)b.z; p[7] = (bf16)b.w;
      *(bf16x8*)(dst) = p;
    }
    return;
  }

  const bool is_q = (bid >= 2048);
  const int row = is_q ? (bid - 2048) : bid;
  const float* xr = (is_q ? qsrc : x) + (size_t)row * E_DIM;
  const float* w = is_q ? lnqw : lnxw;
  const float* bvec = is_q ? lnqb : lnxb;
  const int posrow = is_q ? row : (row & (N_DIM - 1));

  float4 v[4];
  float s1 = 0.f, s2 = 0.f;
#pragma unroll
  for (int j = 0; j < 4; ++j) {
    v[j] = *(const float4*)(xr + j * 1024 + tid * 4);
    s1 += v[j].x + v[j].y + v[j].z + v[j].w;
    s2 += v[j].x * v[j].x + v[j].y * v[j].y + v[j].z * v[j].z + v[j].w * v[j].w;
  }
  s1 = wave_sum(s1); s2 = wave_sum(s2);
  __shared__ float red[8];
  if (lane == 0) { red[wid] = s1; red[wid + 4] = s2; }
  __syncthreads();
  s1 = red[0] + red[1] + red[2] + red[3];
  s2 = red[4] + red[5] + red[6] + red[7];
  const float mean = s1 * (1.f / E_DIM);
  const float var = s2 * (1.f / E_DIM) - mean * mean;
  const float rs = rsqrtf(var + 1e-5f);
#pragma unroll
  for (int j = 0; j < 4; ++j) {
    const int idx = j * 1024 + tid * 4;
    float4 wv = *(const float4*)(w + idx);
    float4 bv = *(const float4*)(bvec + idx);
    float4 pv = *(const float4*)(pos + (size_t)posrow * E_DIM + idx);
    float y0 = (v[j].x - mean) * rs * wv.x + bv.x;
    float y1 = (v[j].y - mean) * rs * wv.y + bv.y;
    float y2 = (v[j].z - mean) * rs * wv.z + bv.z;
    float y3 = (v[j].w - mean) * rs * wv.w + bv.w;
    if (is_q) {
      bf16x4 a;
      a[0] = (bf16)(y0 + pv.x); a[1] = (bf16)(y1 + pv.y);
      a[2] = (bf16)(y2 + pv.z); a[3] = (bf16)(y3 + pv.w);
      *(bf16x4*)(qin + (size_t)row * E_DIM + idx) = a;
    } else {
      bf16x4 a; a[0] = (bf16)y0; a[1] = (bf16)y1; a[2] = (bf16)y2; a[3] = (bf16)y3;
      *(bf16x4*)(kv + (size_t)row * E_DIM + idx) = a;
      bf16x4 c; c[0] = (bf16)(y0 + pv.x); c[1] = (bf16)(y1 + pv.y);
      c[2] = (bf16)(y2 + pv.z); c[3] = (bf16)(y3 + pv.w);
      *(bf16x4*)(kin + (size_t)row * E_DIM + idx) = c;
    }
  }
}

// ---------------- PV: o = probs @ v (per (b,h)) ----------------
__global__ __launch_bounds__(256, 2)
void gemm_pv(const bf16* __restrict__ probs, const bf16* __restrict__ vt,
             bf16* __restrict__ Cb) {
  __shared__ __align__(16) bf16 As[8192];
  __shared__ __align__(16) bf16 Bs[8192];
  const int tid = threadIdx.x;
  const int wid = tid >> 6;
  const int lane = tid & 63;

  const int z = blockIdx.z;
  const bf16* A = probs + (size_t)z * (M_DIM * N_DIM);  // lda=256
  const bf16* B = vt + (size_t)z * D_DIM * N_DIM;       // ldb=256

  const bf16* Arow = A + (size_t)(blockIdx.y * 128) * N_DIM;
  const bf16* Brow = B;  // D=128 -> single col tile

  floatx4 acc[4][4];
#pragma unroll
  for (int i = 0; i < 4; ++i)
#pragma unroll
    for (int j = 0; j < 4; ++j) acc[i][j] = (floatx4){0.f, 0.f, 0.f, 0.f};

  gemm_core_small(Arow, Brow, N_DIM, N_DIM, 8, As, Bs, acc, wid, lane);

  const int mb = blockIdx.y * 128 + (wid >> 1) * 64 + (lane >> 4) * 4;
  const int nb = (wid & 1) * 64 + (lane & 15);
  const int zb_ = z >> 5, zh_ = z & 31;
#pragma unroll
  for (int tr = 0; tr < 4; ++tr) {
#pragma unroll
    for (int tc = 0; tc < 4; ++tc) {
      const int row0 = mb + tr * 16;
      const int col = nb + tc * 16;
      floatx4 a = acc[tr][tc];
#pragma unroll
      for (int r = 0; r < 4; ++r)
        Cb[(size_t)zb_ * M_DIM * E_DIM + (size_t)(row0 + r) * E_DIM + zh_ * D_DIM + col] =
            (bf16)a[r];
    }
  }
}

extern "C" void kernel_launch(void* const* d_in, const int* in_sizes, int n_in,
                              void* d_out, int out_size, void* d_ws, size_t ws_size,
                              hipStream_t stream) {
  const float* x = (const float*)d_in[0];
  const float* query = (const float*)d_in[1];
  const float* pos = (const float*)d_in[2];
  const float* ln_q_w = (const float*)d_in[3];
  const float* ln_q_b = (const float*)d_in[4];
  const float* ln_kv_w = (const float*)d_in[5];
  const float* ln_kv_b = (const float*)d_in[6];
  const float* Wqkv_f = (const float*)d_in[7];
  const float* bqkv = (const float*)d_in[8];
  const float* Wout_f = (const float*)d_in[9];
  const float* bout = (const float*)d_in[10];

  char* ws = (char*)d_ws;
  bf16* Wqkv = (bf16*)(ws + 0);            // 100,663,296 (dead after proj256)
  bf16* Wout = (bf16*)(ws + 100663296);    // 33,554,432
  bf16* kv   = (bf16*)(ws + 134217728);    // 16,777,216
  bf16* kin  = (bf16*)(ws + 150994944);    // 16,777,216
  bf16* qin  = (bf16*)(ws + 167772160);    //  2,097,152
  bf16* qp   = (bf16*)(ws + 169869312);    //  2,097,152
  bf16* kp   = (bf16*)(ws + 171966464);    // 16,777,216
  bf16* vt   = (bf16*)(ws + 188743680);    // 16,777,216
  float* qpart = (float*)(ws + 205520896); // 67,108,864 q split-K partials
  bf16* probs = (bf16*)(ws + 0);           // 33,554,432 (alias dead Wqkv)
  bf16* obuf = (bf16*)(ws + 67108864);     // 16,777,216 (alias Wqkv tail)

  float* out = (float*)d_out;
  float* out2 = out + (size_t)B_DIM * M_DIM * E_DIM;

  // LN(x), LN(q), weight conversion: one merged launch
  prep_kernel<<<6400, 256, 0, stream>>>(x, ln_kv_w, ln_kv_b, pos, kv, kin,
                                        query, ln_q_w, ln_q_b, qin,
                                        Wqkv_f, Wqkv, Wout_f, Wout);

  // k/v projections (256 blocks = one wave) + q split-K partials
  proj256<<<256, 512, 0, stream>>>(qin, kin, kv, Wqkv, bqkv, qpart, kp, vt);
  qreduce_kernel<<<1024, 256, 0, stream>>>(qpart, bqkv, qp);

  // scores + softmax fused -> bf16 probs (one wave)
  scores_sm<<<256, 512, 0, stream>>>(qp, kp, probs, 0.08838834764831845f);
  probs_mean<<<2048, 256, 0, stream>>>(probs, out2);

  // o = probs @ v (per (b,h): 256x128x256)
  gemm_pv<<<dim3(1, 2, 256), 256, 0, stream>>>(probs, vt, obuf);

  // out = o @ Wout^T + bias: 128x256 tiles, no split-K, one wave
  outproj128<<<256, 512, 0, stream>>>(obuf, Wout, bout, out);
}